// Round 11
// baseline (457.823 us; speedup 1.0000x reference)
//
#include <hip/hip_runtime.h>
#include <math.h>

#define B_   4
#define S_   2048
#define AD   128
#define NH   4
#define HD   32
#define TK   32
#define SEG  1048576            /* 8192*128 */
#define CAP  192                /* candidate capacity per row */
#define CHD  8                  /* heads per score chunk */

#define OFF_PROJ 0
#define OFF_Q    (1 * SEG)
#define OFF_K    (2 * SEG)
#define OFF_V    (3 * SEG)
#define OFF_ATT  (4 * SEG)
#define OFF_T    (5 * SEG)
#define OFF_SB   (6 * SEG)
#define OFF_CAT  (7 * SEG)      /* 2*SEG floats */

__device__ float g_ws[9 * SEG];
__device__ unsigned short g_sp[CHD * S_ * S_];  /* 64 MB u16 prefix chunk, reused */

__device__ __forceinline__ unsigned f2key(float s) {
    unsigned u = __float_as_uint(s);
    return (u & 0x80000000u) ? ~u : (u | 0x80000000u);
}
__device__ __forceinline__ float key2f(unsigned k) {
    unsigned u = (k & 0x80000000u) ? (k & 0x7FFFFFFFu) : ~k;
    return __uint_as_float(u);
}

// Y[M x 128] = X[M x KD] @ W[128 x KD]^T + b  (R5 known-good, pad 68)
template <int KD>
__global__ __launch_bounds__(256)
void lin_kernel(const float* __restrict__ Xext, int xoff,
                const float* __restrict__ W, const float* __restrict__ Bv,
                int yoff)
{
    const float* X = Xext ? Xext : (const float*)(g_ws + xoff);
    float* Y = g_ws + yoff;
    __shared__ float Xs[32][68];
    __shared__ float Ws[32][68];
    const int bm = blockIdx.x * 64;
    const int bn = blockIdx.y * 64;
    const int t  = threadIdx.x;
    const int tx = t & 15, ty = t >> 4;
    const int sr = t >> 3, sc4 = t & 7;
    float acc[4][4] = {};
    for (int kk = 0; kk < KD; kk += 32) {
        #pragma unroll
        for (int it = 0; it < 2; ++it) {
            int rr = sr + it * 32;
            float4 xa = *(const float4*)(X + (size_t)(bm + rr) * KD + kk + sc4 * 4);
            float4 wa = *(const float4*)(W + (size_t)(bn + rr) * KD + kk + sc4 * 4);
            Xs[sc4*4+0][rr] = xa.x; Xs[sc4*4+1][rr] = xa.y;
            Xs[sc4*4+2][rr] = xa.z; Xs[sc4*4+3][rr] = xa.w;
            Ws[sc4*4+0][rr] = wa.x; Ws[sc4*4+1][rr] = wa.y;
            Ws[sc4*4+2][rr] = wa.z; Ws[sc4*4+3][rr] = wa.w;
        }
        __syncthreads();
        #pragma unroll
        for (int kc = 0; kc < 32; ++kc) {
            float4 a4 = *(const float4*)&Xs[kc][ty * 4];
            float4 b4 = *(const float4*)&Ws[kc][tx * 4];
            float a[4] = {a4.x, a4.y, a4.z, a4.w};
            float bb[4] = {b4.x, b4.y, b4.z, b4.w};
            #pragma unroll
            for (int i = 0; i < 4; ++i)
                #pragma unroll
                for (int j = 0; j < 4; ++j)
                    acc[i][j] = fmaf(a[i], bb[j], acc[i][j]);
        }
        __syncthreads();
    }
    #pragma unroll
    for (int i = 0; i < 4; ++i) {
        int row = bm + ty * 4 + i;
        int col = bn + tx * 4;
        float4 o;
        o.x = acc[i][0] + Bv[col + 0]; o.y = acc[i][1] + Bv[col + 1];
        o.z = acc[i][2] + Bv[col + 2]; o.w = acc[i][3] + Bv[col + 3];
        *(float4*)(Y + (size_t)row * AD + col) = o;
    }
}

template <int KD>
__global__ __launch_bounds__(256)
void lin3_kernel(int xoff,
                 const float* __restrict__ W0, const float* __restrict__ B0, int y0,
                 const float* __restrict__ W1, const float* __restrict__ B1, int y1,
                 const float* __restrict__ W2, const float* __restrict__ B2, int y2)
{
    const int z = blockIdx.z;
    const float* X = (const float*)(g_ws + xoff);
    const float* W = (z == 0) ? W0 : (z == 1) ? W1 : W2;
    const float* Bv = (z == 0) ? B0 : (z == 1) ? B1 : B2;
    float* Y = g_ws + ((z == 0) ? y0 : (z == 1) ? y1 : y2);
    __shared__ float Xs[32][68];
    __shared__ float Ws[32][68];
    const int bm = blockIdx.x * 64;
    const int bn = blockIdx.y * 64;
    const int t  = threadIdx.x;
    const int tx = t & 15, ty = t >> 4;
    const int sr = t >> 3, sc4 = t & 7;
    float acc[4][4] = {};
    for (int kk = 0; kk < KD; kk += 32) {
        #pragma unroll
        for (int it = 0; it < 2; ++it) {
            int rr = sr + it * 32;
            float4 xa = *(const float4*)(X + (size_t)(bm + rr) * KD + kk + sc4 * 4);
            float4 wa = *(const float4*)(W + (size_t)(bn + rr) * KD + kk + sc4 * 4);
            Xs[sc4*4+0][rr] = xa.x; Xs[sc4*4+1][rr] = xa.y;
            Xs[sc4*4+2][rr] = xa.z; Xs[sc4*4+3][rr] = xa.w;
            Ws[sc4*4+0][rr] = wa.x; Ws[sc4*4+1][rr] = wa.y;
            Ws[sc4*4+2][rr] = wa.z; Ws[sc4*4+3][rr] = wa.w;
        }
        __syncthreads();
        #pragma unroll
        for (int kc = 0; kc < 32; ++kc) {
            float4 a4 = *(const float4*)&Xs[kc][ty * 4];
            float4 b4 = *(const float4*)&Ws[kc][tx * 4];
            float a[4] = {a4.x, a4.y, a4.z, a4.w};
            float bb[4] = {b4.x, b4.y, b4.z, b4.w};
            #pragma unroll
            for (int i = 0; i < 4; ++i)
                #pragma unroll
                for (int j = 0; j < 4; ++j)
                    acc[i][j] = fmaf(a[i], bb[j], acc[i][j]);
        }
        __syncthreads();
    }
    #pragma unroll
    for (int i = 0; i < 4; ++i) {
        int row = bm + ty * 4 + i;
        int col = bn + tx * 4;
        float4 o;
        o.x = acc[i][0] + Bv[col + 0]; o.y = acc[i][1] + Bv[col + 1];
        o.z = acc[i][2] + Bv[col + 2]; o.w = acc[i][3] + Bv[col + 3];
        *(float4*)(Y + (size_t)row * AD + col) = o;
    }
}

// Prefix kernel: g_sp[zh][q][k] = f2key(scale*Q·K) >> 16 for head chunk*CHD+zh.
// fmaf chain kc ascending, scale last — topk's rescore reproduces this chain
// bit-identically (strict fmaf, no reassociation at -O3 without fast-math).
__global__ __launch_bounds__(256)
void score_kernel(int qoff, int koff, int chunk)
{
    const int zh = blockIdx.z;
    const int hh = chunk * CHD + zh, b = hh >> 2, h = hh & 3;
    const float* Qb = g_ws + qoff + (size_t)b * S_ * AD + h * HD;
    const float* Kb = g_ws + koff + (size_t)b * S_ * AD + h * HD;
    unsigned short* Sc = g_sp + (size_t)zh * S_ * S_;
    __shared__ float Qs[32][68];
    __shared__ float Ks[32][68];
    const int t = threadIdx.x, tx = t & 15, ty = t >> 4;
    const int sr = t >> 3, sc4 = t & 7;
    const int q0 = blockIdx.y * 64, k0 = blockIdx.x * 64;
    #pragma unroll
    for (int it = 0; it < 2; ++it) {
        int rr = sr + it * 32;
        float4 qa = *(const float4*)(Qb + (size_t)(q0 + rr) * AD + sc4 * 4);
        float4 ka = *(const float4*)(Kb + (size_t)(k0 + rr) * AD + sc4 * 4);
        Qs[sc4*4+0][rr] = qa.x; Qs[sc4*4+1][rr] = qa.y;
        Qs[sc4*4+2][rr] = qa.z; Qs[sc4*4+3][rr] = qa.w;
        Ks[sc4*4+0][rr] = ka.x; Ks[sc4*4+1][rr] = ka.y;
        Ks[sc4*4+2][rr] = ka.z; Ks[sc4*4+3][rr] = ka.w;
    }
    __syncthreads();
    float acc[4][4] = {};
    #pragma unroll
    for (int kc = 0; kc < 32; ++kc) {
        float4 a4 = *(const float4*)&Qs[kc][ty * 4];
        float4 b4 = *(const float4*)&Ks[kc][tx * 4];
        float a[4] = {a4.x, a4.y, a4.z, a4.w};
        float bb[4] = {b4.x, b4.y, b4.z, b4.w};
        #pragma unroll
        for (int i = 0; i < 4; ++i)
            #pragma unroll
            for (int j = 0; j < 4; ++j)
                acc[i][j] = fmaf(a[i], bb[j], acc[i][j]);
    }
    const float scale = 0.17677669529663688f;  // 1/sqrt(32)
    #pragma unroll
    for (int i = 0; i < 4; ++i) {
        ushort4 o;
        o.x = (unsigned short)(f2key(acc[i][0] * scale) >> 16);
        o.y = (unsigned short)(f2key(acc[i][1] * scale) >> 16);
        o.z = (unsigned short)(f2key(acc[i][2] * scale) >> 16);
        o.w = (unsigned short)(f2key(acc[i][3] * scale) >> 16);
        *(ushort4*)(Sc + (size_t)(q0 + ty * 4 + i) * S_ + k0 + tx * 4) = o;
    }
}

// One wave per q-row. Prefix threshold (t16 = 32nd-largest lane-max prefix =>
// provable top-32 superset incl. ties), candidates re-scored EXACTLY
// (bit-identical fmaf chain), rank-by-count order == lax.top_k.
// Phase-scoped registers: prefix regs die before q-row regs load.
__global__ __launch_bounds__(256)
void topk_kernel(int qoff, int koff, int voff, int ooff, int chunk)
{
    __shared__ unsigned cnd[4][CAP];
    __shared__ unsigned long long sve[4][CAP];
    __shared__ float    wsel[4][32];
    __shared__ unsigned jsel[4][32];

    const int wid  = threadIdx.x >> 6;
    const int lane = threadIdx.x & 63;
    const int gr   = blockIdx.x * 4 + wid;     // 0..CHD*2048-1
    const int zh   = gr >> 11, q = gr & 2047;
    const int hh   = chunk * CHD + zh;
    const int b    = hh >> 2,  h = hh & 3;

    unsigned* cp = cnd[wid];
    unsigned long long* sv = sve[wid];
    float*    wp = wsel[wid];
    unsigned* jp = jsel[wid];

    const unsigned short* Prow = g_sp + (size_t)zh * S_ * S_ + (size_t)q * S_;
    const float* qrow  = g_ws + qoff + ((size_t)b * S_ + q) * AD + h * HD;
    const float* kbase = g_ws + koff + (size_t)b * S_ * AD + h * HD;
    const float* vbase = g_ws + voff + (size_t)b * S_ * AD + h * HD;
    float* O = g_ws + ooff;
    const float scale = 0.17677669529663688f;

    int S = 0;
    {   // ---- phase 1: prefixes -> threshold -> candidate indices (LDS) ----
        unsigned pwv[16];
        unsigned lmax = 0u;
        #pragma unroll
        for (int i = 0; i < 4; ++i) {
            uint4 u = ((const uint4*)Prow)[i * 64 + lane];
            pwv[i*4+0] = u.x; pwv[i*4+1] = u.y; pwv[i*4+2] = u.z; pwv[i*4+3] = u.w;
        }
        #pragma unroll
        for (int w = 0; w < 16; ++w) {
            unsigned lo = pwv[w] & 0xFFFFu, hi = pwv[w] >> 16;
            unsigned m = (lo > hi) ? lo : hi;
            lmax = (m > lmax) ? m : lmax;
        }
        unsigned bs = lmax;
        #pragma unroll
        for (int k = 2; k <= 64; k <<= 1) {
            #pragma unroll
            for (int j = k >> 1; j > 0; j >>= 1) {
                unsigned o = (unsigned)__shfl_xor((int)bs, j);
                bool keepmin = (((lane & k) == 0) == ((lane & j) == 0));
                bs = keepmin ? (bs < o ? bs : o) : (bs > o ? bs : o);
            }
        }
        const unsigned t16 = (unsigned)__shfl((int)bs, 32);

        asm volatile("s_waitcnt lgkmcnt(0)" ::: "memory");
        const unsigned long long lt = (1ull << lane) - 1ull;
        #pragma unroll
        for (int i = 0; i < 4; ++i)
            #pragma unroll
            for (int j = 0; j < 4; ++j)
                #pragma unroll
                for (int hf = 0; hf < 2; ++hf) {
                    unsigned w = pwv[i*4+j];
                    unsigned p = hf ? (w >> 16) : (w & 0xFFFFu);
                    bool pred = p >= t16;
                    unsigned long long m = __ballot(pred);
                    int slot = S + __popcll(m & lt);
                    if (pred && slot < CAP)
                        cp[slot] = (unsigned)(512*i + 8*lane + 2*j + hf);
                    S += __popcll(m);
                }
        asm volatile("s_waitcnt lgkmcnt(0)" ::: "memory");
    }   // pwv dead here

    // ---- phase 2: q row into regs ----
    float qv[32];
    #pragma unroll
    for (int g = 0; g < 8; ++g) {
        float4 t4 = ((const float4*)qrow)[g];
        qv[g*4+0] = t4.x; qv[g*4+1] = t4.y; qv[g*4+2] = t4.z; qv[g*4+3] = t4.w;
    }

    if (S <= CAP) {
        // ---- exact re-score of candidates (bit-identical chain) ----
        unsigned long long pk[3];
        #pragma unroll
        for (int u = 0; u < 3; ++u) {
            int i = lane + u * 64;
            pk[u] = 0ull;
            if (i < S) {
                unsigned ji = cp[i];
                const float4* kp = (const float4*)(kbase + (size_t)ji * AD);
                float s = 0.f;
                #pragma unroll
                for (int g = 0; g < 8; ++g) {
                    float4 kv = kp[g];
                    s = fmaf(qv[g*4+0], kv.x, s); s = fmaf(qv[g*4+1], kv.y, s);
                    s = fmaf(qv[g*4+2], kv.z, s); s = fmaf(qv[g*4+3], kv.w, s);
                }
                unsigned key = f2key(s * scale);
                pk[u] = ((unsigned long long)key << 32) | (unsigned)(2047 - ji);
                sv[i] = pk[u];
            }
        }
        asm volatile("s_waitcnt lgkmcnt(0)" ::: "memory");

        unsigned long long mk = pk[0];
        mk = (pk[1] > mk) ? pk[1] : mk;
        mk = (pk[2] > mk) ? pk[2] : mk;
        #pragma unroll
        for (int off = 1; off < 64; off <<= 1) {
            unsigned long long o =
                (unsigned long long)__shfl_xor((long long)mk, off);
            mk = (o > mk) ? o : mk;
        }
        const float Mf = key2f((unsigned)(mk >> 32));

        if (S <= 64) {
            unsigned long long pi = pk[0];
            int rank = 0;
            for (int jx = 0; jx < S; ++jx)
                rank += (sv[jx] > pi) ? 1 : 0;
            float e = 0.f; unsigned ji = 0;
            if (lane < S && rank < TK) {
                e = __expf(key2f((unsigned)(pi >> 32)) - Mf);
                ji = 2047u - (unsigned)(pi & 0xFFFFFFFFull);
            }
            float esum = e;
            #pragma unroll
            for (int off = 1; off < 64; off <<= 1) esum += __shfl_xor(esum, off);
            if (lane < S && rank < TK) { wp[rank] = e / esum; jp[rank] = ji; }
        } else {
            int rk[3]; float ee[3]; unsigned jj[3];
            float esum = 0.f;
            #pragma unroll
            for (int u = 0; u < 3; ++u) { rk[u] = 0; ee[u] = 0.f; jj[u] = 0; }
            for (int jx = 0; jx < S; ++jx) {
                unsigned long long pj = sv[jx];
                #pragma unroll
                for (int u = 0; u < 3; ++u)
                    rk[u] += (pj > pk[u]) ? 1 : 0;
            }
            #pragma unroll
            for (int u = 0; u < 3; ++u) {
                int i = lane + u * 64;
                if (i < S && rk[u] < TK) {
                    ee[u] = __expf(key2f((unsigned)(pk[u] >> 32)) - Mf);
                    jj[u] = 2047u - (unsigned)(pk[u] & 0xFFFFFFFFull);
                    esum += ee[u];
                }
            }
            #pragma unroll
            for (int off = 1; off < 64; off <<= 1) esum += __shfl_xor(esum, off);
            #pragma unroll
            for (int u = 0; u < 3; ++u) {
                int i = lane + u * 64;
                if (i < S && rk[u] < TK) { wp[rk[u]] = ee[u] / esum; jp[rk[u]] = jj[u]; }
            }
        }
    } else {
        // ---- exact fallback: full recompute + iterative argmax ----
        unsigned keys[32];
        #pragma unroll
        for (int t = 0; t < 32; ++t) {
            const float4* kp = (const float4*)(kbase + (size_t)(t * 64 + lane) * AD);
            float s = 0.f;
            #pragma unroll
            for (int g = 0; g < 8; ++g) {
                float4 kv = kp[g];
                s = fmaf(qv[g*4+0], kv.x, s); s = fmaf(qv[g*4+1], kv.y, s);
                s = fmaf(qv[g*4+2], kv.z, s); s = fmaf(qv[g*4+3], kv.w, s);
            }
            keys[t] = f2key(s * scale);
        }
        unsigned consumed = 0u;
        unsigned mfk = 0u;
        for (int i = 0; i < TK; ++i) {
            unsigned bk = 0u; unsigned gj = 0xFFFFFFFFu;
            #pragma unroll
            for (int t = 0; t < 32; ++t) {
                if (((consumed >> t) & 1u) == 0u) {
                    unsigned kk = keys[t];
                    unsigned j = (unsigned)(t * 64 + lane);
                    if (kk > bk || (kk == bk && j < gj)) { bk = kk; gj = j; }
                }
            }
            #pragma unroll
            for (int off = 1; off < 64; off <<= 1) {
                unsigned ok = (unsigned)__shfl_xor((int)bk, off);
                unsigned oj = (unsigned)__shfl_xor((int)gj, off);
                if (ok > bk || (ok == bk && oj < gj)) { bk = ok; gj = oj; }
            }
            if (i == 0) mfk = bk;
            if ((gj & 63u) == (unsigned)lane && gj != 0xFFFFFFFFu)
                consumed |= (1u << (gj >> 6));
            if (lane == 0) { wp[i] = key2f(bk); jp[i] = gj; }
        }
        asm volatile("s_waitcnt lgkmcnt(0)" ::: "memory");
        const float Mf = key2f(mfk);
        float v = (lane < TK) ? wp[lane] : 0.f;
        float e = (lane < TK) ? __expf(v - Mf) : 0.f;
        float esum = e;
        #pragma unroll
        for (int off = 1; off < 64; off <<= 1) esum += __shfl_xor(esum, off);
        if (lane < TK) wp[lane] = e / esum;
    }
    asm volatile("s_waitcnt lgkmcnt(0)" ::: "memory");

    // ---- out[dd] = sum_i w_i * V[idx_i][dd] ----
    float oacc = 0.f;
    const int dd = lane & 31, half = lane >> 5;
    #pragma unroll
    for (int u2 = 0; u2 < 16; ++u2) {
        int i = half * 16 + u2;
        oacc = fmaf(wp[i], vbase[(size_t)jp[i] * AD + dd], oacc);
    }
    oacc += __shfl_down(oacc, 32);
    if (lane < HD) O[((size_t)b * S_ + q) * AD + h * HD + lane] = oacc;
}

__global__ __launch_bounds__(256)
void concat_kernel()
{
    int i = blockIdx.x * 256 + threadIdx.x;   // over 8192*256
    int row = i >> 8, c = i & 255;
    float v = (c < AD) ? g_ws[OFF_T + row * AD + c]
                       : g_ws[OFF_SB + row * AD + (c - AD)];
    g_ws[OFF_CAT + i] = v;
}

__global__ __launch_bounds__(256)
void fuse_kernel(float* __restrict__ out)
{
    int i = blockIdx.x * 256 + threadIdx.x;   // over 8192*128
    float g = g_ws[OFF_Q + i];
    float f = g_ws[OFF_K + i];
    out[i] = f / (1.0f + expf(-g));           // f * sigmoid(g)
}

extern "C" void kernel_launch(void* const* d_in, const int* in_sizes, int n_in,
                              void* d_out, int out_size, void* d_ws, size_t ws_size,
                              hipStream_t stream)
{
    (void)in_sizes; (void)n_in; (void)d_ws; (void)ws_size; (void)out_size;
    const float* x      = (const float*)d_in[0];
    const float* tp_w   = (const float*)d_in[1];
    const float* tp_b   = (const float*)d_in[2];
    const float* sp_w   = (const float*)d_in[3];
    const float* sp_b   = (const float*)d_in[4];
    const float* gate_w = (const float*)d_in[21];
    const float* gate_b = (const float*)d_in[22];
    const float* fus_w  = (const float*)d_in[23];
    const float* fus_b  = (const float*)d_in[24];

    dim3 gl(128, 2);
    for (int br = 0; br < 2; ++br) {
        const float* pw = br ? sp_w : tp_w;
        const float* pb = br ? sp_b : tp_b;
        int base = 5 + br * 8;
        const float* qw = (const float*)d_in[base + 0];
        const float* qb = (const float*)d_in[base + 1];
        const float* kw = (const float*)d_in[base + 2];
        const float* kb = (const float*)d_in[base + 3];
        const float* vw = (const float*)d_in[base + 4];
        const float* vb = (const float*)d_in[base + 5];
        const float* ow = (const float*)d_in[base + 6];
        const float* ob = (const float*)d_in[base + 7];

        lin_kernel<256><<<gl, 256, 0, stream>>>(x, 0, pw, pb, OFF_PROJ);
        lin3_kernel<128><<<dim3(128, 2, 3), 256, 0, stream>>>(
            OFF_PROJ, qw, qb, OFF_Q, kw, kb, OFF_K, vw, vb, OFF_V);
        for (int chunk = 0; chunk < 2; ++chunk) {
            score_kernel<<<dim3(32, 32, CHD), 256, 0, stream>>>(OFF_Q, OFF_K, chunk);
            topk_kernel<<<CHD * 512, 256, 0, stream>>>(OFF_Q, OFF_K, OFF_V,
                                                       OFF_ATT, chunk);
        }
        lin_kernel<128><<<gl, 256, 0, stream>>>(nullptr, OFF_ATT, ow, ob,
                                                br ? OFF_SB : OFF_T);
    }
    concat_kernel<<<8192, 256, 0, stream>>>();
    lin3_kernel<256><<<dim3(128, 2, 2), 256, 0, stream>>>(
        OFF_CAT, gate_w, gate_b, OFF_Q, fus_w, fus_b, OFF_K,
        (const float*)nullptr, (const float*)nullptr, 0);
    fuse_kernel<<<4096, 256, 0, stream>>>((float*)d_out);
}

// Round 13
// 378.431 us; speedup vs baseline: 1.2098x; 1.2098x over previous
//
#include <hip/hip_runtime.h>
#include <math.h>

#define B_   4
#define S_   2048
#define AD   128
#define NH   4
#define HD   32
#define TK   32
#define SEG  1048576            /* 8192*128 */
#define CAP  192                /* candidate capacity per row */
#define CHD  8                  /* heads per score chunk */

#define OFF_PROJ 0
#define OFF_Q    (1 * SEG)
#define OFF_K    (2 * SEG)
#define OFF_V    (3 * SEG)
#define OFF_ATT  (4 * SEG)
#define OFF_T    (5 * SEG)
#define OFF_SB   (6 * SEG)
#define OFF_CAT  (7 * SEG)      /* 2*SEG floats */

__device__ float g_ws[9 * SEG];
__device__ unsigned short g_sp[CHD * S_ * S_];  /* 64 MB u16 prefix chunk, reused */

__device__ __forceinline__ unsigned f2key(float s) {
    unsigned u = __float_as_uint(s);
    return (u & 0x80000000u) ? ~u : (u | 0x80000000u);
}
__device__ __forceinline__ float key2f(unsigned k) {
    unsigned u = (k & 0x80000000u) ? (k & 0x7FFFFFFFu) : ~k;
    return __uint_as_float(u);
}

// Y[M x 128] = X[M x KD] @ W[128 x KD]^T + b  (R5 known-good, pad 68)
template <int KD>
__global__ __launch_bounds__(256)
void lin_kernel(const float* __restrict__ Xext, int xoff,
                const float* __restrict__ W, const float* __restrict__ Bv,
                int yoff)
{
    const float* X = Xext ? Xext : (const float*)(g_ws + xoff);
    float* Y = g_ws + yoff;
    __shared__ float Xs[32][68];
    __shared__ float Ws[32][68];
    const int bm = blockIdx.x * 64;
    const int bn = blockIdx.y * 64;
    const int t  = threadIdx.x;
    const int tx = t & 15, ty = t >> 4;
    const int sr = t >> 3, sc4 = t & 7;
    float acc[4][4] = {};
    for (int kk = 0; kk < KD; kk += 32) {
        #pragma unroll
        for (int it = 0; it < 2; ++it) {
            int rr = sr + it * 32;
            float4 xa = *(const float4*)(X + (size_t)(bm + rr) * KD + kk + sc4 * 4);
            float4 wa = *(const float4*)(W + (size_t)(bn + rr) * KD + kk + sc4 * 4);
            Xs[sc4*4+0][rr] = xa.x; Xs[sc4*4+1][rr] = xa.y;
            Xs[sc4*4+2][rr] = xa.z; Xs[sc4*4+3][rr] = xa.w;
            Ws[sc4*4+0][rr] = wa.x; Ws[sc4*4+1][rr] = wa.y;
            Ws[sc4*4+2][rr] = wa.z; Ws[sc4*4+3][rr] = wa.w;
        }
        __syncthreads();
        #pragma unroll
        for (int kc = 0; kc < 32; ++kc) {
            float4 a4 = *(const float4*)&Xs[kc][ty * 4];
            float4 b4 = *(const float4*)&Ws[kc][tx * 4];
            float a[4] = {a4.x, a4.y, a4.z, a4.w};
            float bb[4] = {b4.x, b4.y, b4.z, b4.w};
            #pragma unroll
            for (int i = 0; i < 4; ++i)
                #pragma unroll
                for (int j = 0; j < 4; ++j)
                    acc[i][j] = fmaf(a[i], bb[j], acc[i][j]);
        }
        __syncthreads();
    }
    #pragma unroll
    for (int i = 0; i < 4; ++i) {
        int row = bm + ty * 4 + i;
        int col = bn + tx * 4;
        float4 o;
        o.x = acc[i][0] + Bv[col + 0]; o.y = acc[i][1] + Bv[col + 1];
        o.z = acc[i][2] + Bv[col + 2]; o.w = acc[i][3] + Bv[col + 3];
        *(float4*)(Y + (size_t)row * AD + col) = o;
    }
}

template <int KD>
__global__ __launch_bounds__(256)
void lin3_kernel(int xoff,
                 const float* __restrict__ W0, const float* __restrict__ B0, int y0,
                 const float* __restrict__ W1, const float* __restrict__ B1, int y1,
                 const float* __restrict__ W2, const float* __restrict__ B2, int y2)
{
    const int z = blockIdx.z;
    const float* X = (const float*)(g_ws + xoff);
    const float* W = (z == 0) ? W0 : (z == 1) ? W1 : W2;
    const float* Bv = (z == 0) ? B0 : (z == 1) ? B1 : B2;
    float* Y = g_ws + ((z == 0) ? y0 : (z == 1) ? y1 : y2);
    __shared__ float Xs[32][68];
    __shared__ float Ws[32][68];
    const int bm = blockIdx.x * 64;
    const int bn = blockIdx.y * 64;
    const int t  = threadIdx.x;
    const int tx = t & 15, ty = t >> 4;
    const int sr = t >> 3, sc4 = t & 7;
    float acc[4][4] = {};
    for (int kk = 0; kk < KD; kk += 32) {
        #pragma unroll
        for (int it = 0; it < 2; ++it) {
            int rr = sr + it * 32;
            float4 xa = *(const float4*)(X + (size_t)(bm + rr) * KD + kk + sc4 * 4);
            float4 wa = *(const float4*)(W + (size_t)(bn + rr) * KD + kk + sc4 * 4);
            Xs[sc4*4+0][rr] = xa.x; Xs[sc4*4+1][rr] = xa.y;
            Xs[sc4*4+2][rr] = xa.z; Xs[sc4*4+3][rr] = xa.w;
            Ws[sc4*4+0][rr] = wa.x; Ws[sc4*4+1][rr] = wa.y;
            Ws[sc4*4+2][rr] = wa.z; Ws[sc4*4+3][rr] = wa.w;
        }
        __syncthreads();
        #pragma unroll
        for (int kc = 0; kc < 32; ++kc) {
            float4 a4 = *(const float4*)&Xs[kc][ty * 4];
            float4 b4 = *(const float4*)&Ws[kc][tx * 4];
            float a[4] = {a4.x, a4.y, a4.z, a4.w};
            float bb[4] = {b4.x, b4.y, b4.z, b4.w};
            #pragma unroll
            for (int i = 0; i < 4; ++i)
                #pragma unroll
                for (int j = 0; j < 4; ++j)
                    acc[i][j] = fmaf(a[i], bb[j], acc[i][j]);
        }
        __syncthreads();
    }
    #pragma unroll
    for (int i = 0; i < 4; ++i) {
        int row = bm + ty * 4 + i;
        int col = bn + tx * 4;
        float4 o;
        o.x = acc[i][0] + Bv[col + 0]; o.y = acc[i][1] + Bv[col + 1];
        o.z = acc[i][2] + Bv[col + 2]; o.w = acc[i][3] + Bv[col + 3];
        *(float4*)(Y + (size_t)row * AD + col) = o;
    }
}

// Prefix kernel: g_sp[zh][q][k] = f2key(scale*Q·K) >> 16 for head chunk*CHD+zh.
// fmaf chain kc ascending, scale last — topk's rescore reproduces this chain
// bit-identically (strict fmaf, no reassociation at -O3 without fast-math).
__global__ __launch_bounds__(256)
void score_kernel(int qoff, int koff, int chunk)
{
    const int zh = blockIdx.z;
    const int hh = chunk * CHD + zh, b = hh >> 2, h = hh & 3;
    const float* Qb = g_ws + qoff + (size_t)b * S_ * AD + h * HD;
    const float* Kb = g_ws + koff + (size_t)b * S_ * AD + h * HD;
    unsigned short* Sc = g_sp + (size_t)zh * S_ * S_;
    __shared__ float Qs[32][68];
    __shared__ float Ks[32][68];
    const int t = threadIdx.x, tx = t & 15, ty = t >> 4;
    const int sr = t >> 3, sc4 = t & 7;
    const int q0 = blockIdx.y * 64, k0 = blockIdx.x * 64;
    #pragma unroll
    for (int it = 0; it < 2; ++it) {
        int rr = sr + it * 32;
        float4 qa = *(const float4*)(Qb + (size_t)(q0 + rr) * AD + sc4 * 4);
        float4 ka = *(const float4*)(Kb + (size_t)(k0 + rr) * AD + sc4 * 4);
        Qs[sc4*4+0][rr] = qa.x; Qs[sc4*4+1][rr] = qa.y;
        Qs[sc4*4+2][rr] = qa.z; Qs[sc4*4+3][rr] = qa.w;
        Ks[sc4*4+0][rr] = ka.x; Ks[sc4*4+1][rr] = ka.y;
        Ks[sc4*4+2][rr] = ka.z; Ks[sc4*4+3][rr] = ka.w;
    }
    __syncthreads();
    float acc[4][4] = {};
    #pragma unroll
    for (int kc = 0; kc < 32; ++kc) {
        float4 a4 = *(const float4*)&Qs[kc][ty * 4];
        float4 b4 = *(const float4*)&Ks[kc][tx * 4];
        float a[4] = {a4.x, a4.y, a4.z, a4.w};
        float bb[4] = {b4.x, b4.y, b4.z, b4.w};
        #pragma unroll
        for (int i = 0; i < 4; ++i)
            #pragma unroll
            for (int j = 0; j < 4; ++j)
                acc[i][j] = fmaf(a[i], bb[j], acc[i][j]);
    }
    const float scale = 0.17677669529663688f;  // 1/sqrt(32)
    #pragma unroll
    for (int i = 0; i < 4; ++i) {
        ushort4 o;
        o.x = (unsigned short)(f2key(acc[i][0] * scale) >> 16);
        o.y = (unsigned short)(f2key(acc[i][1] * scale) >> 16);
        o.z = (unsigned short)(f2key(acc[i][2] * scale) >> 16);
        o.w = (unsigned short)(f2key(acc[i][3] * scale) >> 16);
        *(ushort4*)(Sc + (size_t)(q0 + ty * 4 + i) * S_ + k0 + tx * 4) = o;
    }
}

// One wave per q-row (R11 structure, passed). Prefix threshold (t16 = 32nd-
// largest lane-max prefix => provable top-32 superset incl. ties), candidates
// re-scored EXACTLY (bit-identical fmaf chain), rank-by-count == lax.top_k.
// Fallback (S>CAP, never taken in practice) recomputes scores on the fly —
// no keys[32] array, so it cannot inflate the hot path's VGPR allocation.
__global__ __launch_bounds__(256)
void topk_kernel(int qoff, int koff, int voff, int ooff, int chunk)
{
    __shared__ unsigned cnd[4][CAP];
    __shared__ unsigned long long sve[4][CAP];
    __shared__ float    wsel[4][32];
    __shared__ unsigned jsel[4][32];

    const int wid  = threadIdx.x >> 6;
    const int lane = threadIdx.x & 63;
    const int gr   = blockIdx.x * 4 + wid;     // 0..CHD*2048-1
    const int zh   = gr >> 11, q = gr & 2047;
    const int hh   = chunk * CHD + zh;
    const int b    = hh >> 2,  h = hh & 3;

    unsigned* cp = cnd[wid];
    unsigned long long* sv = sve[wid];
    float*    wp = wsel[wid];
    unsigned* jp = jsel[wid];

    const unsigned short* Prow = g_sp + (size_t)zh * S_ * S_ + (size_t)q * S_;
    const float* qrow  = g_ws + qoff + ((size_t)b * S_ + q) * AD + h * HD;
    const float* kbase = g_ws + koff + (size_t)b * S_ * AD + h * HD;
    const float* vbase = g_ws + voff + (size_t)b * S_ * AD + h * HD;
    float* O = g_ws + ooff;
    const float scale = 0.17677669529663688f;

    int S = 0;
    {   // ---- phase 1: prefixes -> threshold -> candidate indices (LDS) ----
        unsigned pwv[16];
        unsigned lmax = 0u;
        #pragma unroll
        for (int i = 0; i < 4; ++i) {
            uint4 u = ((const uint4*)Prow)[i * 64 + lane];
            pwv[i*4+0] = u.x; pwv[i*4+1] = u.y; pwv[i*4+2] = u.z; pwv[i*4+3] = u.w;
        }
        #pragma unroll
        for (int w = 0; w < 16; ++w) {
            unsigned lo = pwv[w] & 0xFFFFu, hi = pwv[w] >> 16;
            unsigned m = (lo > hi) ? lo : hi;
            lmax = (m > lmax) ? m : lmax;
        }
        unsigned bs = lmax;
        #pragma unroll
        for (int k = 2; k <= 64; k <<= 1) {
            #pragma unroll
            for (int j = k >> 1; j > 0; j >>= 1) {
                unsigned o = (unsigned)__shfl_xor((int)bs, j);
                bool keepmin = (((lane & k) == 0) == ((lane & j) == 0));
                bs = keepmin ? (bs < o ? bs : o) : (bs > o ? bs : o);
            }
        }
        const unsigned t16 = (unsigned)__shfl((int)bs, 32);

        asm volatile("s_waitcnt lgkmcnt(0)" ::: "memory");
        const unsigned long long lt = (1ull << lane) - 1ull;
        #pragma unroll
        for (int i = 0; i < 4; ++i)
            #pragma unroll
            for (int j = 0; j < 4; ++j)
                #pragma unroll
                for (int hf = 0; hf < 2; ++hf) {
                    unsigned w = pwv[i*4+j];
                    unsigned p = hf ? (w >> 16) : (w & 0xFFFFu);
                    bool pred = p >= t16;
                    unsigned long long m = __ballot(pred);
                    int slot = S + __popcll(m & lt);
                    if (pred && slot < CAP)
                        cp[slot] = (unsigned)(512*i + 8*lane + 2*j + hf);
                    S += __popcll(m);
                }
        asm volatile("s_waitcnt lgkmcnt(0)" ::: "memory");
    }   // pwv dead here

    // ---- phase 2: q row into regs ----
    float qv[32];
    #pragma unroll
    for (int g = 0; g < 8; ++g) {
        float4 t4 = ((const float4*)qrow)[g];
        qv[g*4+0] = t4.x; qv[g*4+1] = t4.y; qv[g*4+2] = t4.z; qv[g*4+3] = t4.w;
    }

    if (S <= CAP) {
        // ---- exact re-score of candidates (bit-identical chain) ----
        unsigned long long pk[3];
        #pragma unroll
        for (int u = 0; u < 3; ++u) {
            int i = lane + u * 64;
            pk[u] = 0ull;
            if (i < S) {
                unsigned ji = cp[i];
                const float4* kp = (const float4*)(kbase + (size_t)ji * AD);
                float s = 0.f;
                #pragma unroll
                for (int g = 0; g < 8; ++g) {
                    float4 kv = kp[g];
                    s = fmaf(qv[g*4+0], kv.x, s); s = fmaf(qv[g*4+1], kv.y, s);
                    s = fmaf(qv[g*4+2], kv.z, s); s = fmaf(qv[g*4+3], kv.w, s);
                }
                unsigned key = f2key(s * scale);
                pk[u] = ((unsigned long long)key << 32) | (unsigned)(2047 - ji);
                sv[i] = pk[u];
            }
        }
        asm volatile("s_waitcnt lgkmcnt(0)" ::: "memory");

        unsigned long long mk = pk[0];
        mk = (pk[1] > mk) ? pk[1] : mk;
        mk = (pk[2] > mk) ? pk[2] : mk;
        #pragma unroll
        for (int off = 1; off < 64; off <<= 1) {
            unsigned long long o =
                (unsigned long long)__shfl_xor((long long)mk, off);
            mk = (o > mk) ? o : mk;
        }
        const float Mf = key2f((unsigned)(mk >> 32));

        if (S <= 64) {
            unsigned long long pi = pk[0];
            int rank = 0;
            for (int jx = 0; jx < S; ++jx)
                rank += (sv[jx] > pi) ? 1 : 0;
            float e = 0.f; unsigned ji = 0;
            if (lane < S && rank < TK) {
                e = __expf(key2f((unsigned)(pi >> 32)) - Mf);
                ji = 2047u - (unsigned)(pi & 0xFFFFFFFFull);
            }
            float esum = e;
            #pragma unroll
            for (int off = 1; off < 64; off <<= 1) esum += __shfl_xor(esum, off);
            if (lane < S && rank < TK) { wp[rank] = e / esum; jp[rank] = ji; }
        } else {
            int rk[3]; float ee[3]; unsigned jj[3];
            float esum = 0.f;
            #pragma unroll
            for (int u = 0; u < 3; ++u) { rk[u] = 0; ee[u] = 0.f; jj[u] = 0; }
            for (int jx = 0; jx < S; ++jx) {
                unsigned long long pj = sv[jx];
                #pragma unroll
                for (int u = 0; u < 3; ++u)
                    rk[u] += (pj > pk[u]) ? 1 : 0;
            }
            #pragma unroll
            for (int u = 0; u < 3; ++u) {
                int i = lane + u * 64;
                if (i < S && rk[u] < TK) {
                    ee[u] = __expf(key2f((unsigned)(pk[u] >> 32)) - Mf);
                    jj[u] = 2047u - (unsigned)(pk[u] & 0xFFFFFFFFull);
                    esum += ee[u];
                }
            }
            #pragma unroll
            for (int off = 1; off < 64; off <<= 1) esum += __shfl_xor(esum, off);
            #pragma unroll
            for (int u = 0; u < 3; ++u) {
                int i = lane + u * 64;
                if (i < S && rk[u] < TK) { wp[rk[u]] = ee[u] / esum; jp[rk[u]] = jj[u]; }
            }
        }
    } else {
        // ---- exact fallback (never taken in practice): iterative argmax,
        // scores recomputed per iteration — no keys[32] register array.
        unsigned consumed = 0u;
        unsigned mfk = 0u;
        #pragma unroll 1
        for (int i = 0; i < TK; ++i) {
            unsigned bk = 0u; unsigned gj = 0xFFFFFFFFu;
            #pragma unroll 1
            for (int t = 0; t < 32; ++t) {
                if (((consumed >> t) & 1u) == 0u) {
                    const float4* kp =
                        (const float4*)(kbase + (size_t)(t * 64 + lane) * AD);
                    float s = 0.f;
                    #pragma unroll
                    for (int g = 0; g < 8; ++g) {
                        float4 kv = kp[g];
                        s = fmaf(qv[g*4+0], kv.x, s); s = fmaf(qv[g*4+1], kv.y, s);
                        s = fmaf(qv[g*4+2], kv.z, s); s = fmaf(qv[g*4+3], kv.w, s);
                    }
                    unsigned kk = f2key(s * scale);
                    unsigned j = (unsigned)(t * 64 + lane);
                    if (kk > bk || (kk == bk && j < gj)) { bk = kk; gj = j; }
                }
            }
            #pragma unroll
            for (int off = 1; off < 64; off <<= 1) {
                unsigned ok = (unsigned)__shfl_xor((int)bk, off);
                unsigned oj = (unsigned)__shfl_xor((int)gj, off);
                if (ok > bk || (ok == bk && oj < gj)) { bk = ok; gj = oj; }
            }
            if (i == 0) mfk = bk;
            if ((gj & 63u) == (unsigned)lane && gj != 0xFFFFFFFFu)
                consumed |= (1u << (gj >> 6));
            if (lane == 0) { wp[i] = key2f(bk); jp[i] = gj; }
        }
        asm volatile("s_waitcnt lgkmcnt(0)" ::: "memory");
        const float Mf = key2f(mfk);
        float v = (lane < TK) ? wp[lane] : 0.f;
        float e = (lane < TK) ? __expf(v - Mf) : 0.f;
        float esum = e;
        #pragma unroll
        for (int off = 1; off < 64; off <<= 1) esum += __shfl_xor(esum, off);
        if (lane < TK) wp[lane] = e / esum;
    }
    asm volatile("s_waitcnt lgkmcnt(0)" ::: "memory");

    // ---- out[dd] = sum_i w_i * V[idx_i][dd] ----
    float oacc = 0.f;
    const int dd = lane & 31, half = lane >> 5;
    #pragma unroll
    for (int u2 = 0; u2 < 16; ++u2) {
        int i = half * 16 + u2;
        oacc = fmaf(wp[i], vbase[(size_t)jp[i] * AD + dd], oacc);
    }
    oacc += __shfl_down(oacc, 32);
    if (lane < HD) O[((size_t)b * S_ + q) * AD + h * HD + lane] = oacc;
}

__global__ __launch_bounds__(256)
void concat_kernel()
{
    int i = blockIdx.x * 256 + threadIdx.x;   // over 8192*256
    int row = i >> 8, c = i & 255;
    float v = (c < AD) ? g_ws[OFF_T + row * AD + c]
                       : g_ws[OFF_SB + row * AD + (c - AD)];
    g_ws[OFF_CAT + i] = v;
}

__global__ __launch_bounds__(256)
void fuse_kernel(float* __restrict__ out)
{
    int i = blockIdx.x * 256 + threadIdx.x;   // over 8192*128
    float g = g_ws[OFF_Q + i];
    float f = g_ws[OFF_K + i];
    out[i] = f / (1.0f + expf(-g));           // f * sigmoid(g)
}

extern "C" void kernel_launch(void* const* d_in, const int* in_sizes, int n_in,
                              void* d_out, int out_size, void* d_ws, size_t ws_size,
                              hipStream_t stream)
{
    (void)in_sizes; (void)n_in; (void)d_ws; (void)ws_size; (void)out_size;
    const float* x      = (const float*)d_in[0];
    const float* tp_w   = (const float*)d_in[1];
    const float* tp_b   = (const float*)d_in[2];
    const float* sp_w   = (const float*)d_in[3];
    const float* sp_b   = (const float*)d_in[4];
    const float* gate_w = (const float*)d_in[21];
    const float* gate_b = (const float*)d_in[22];
    const float* fus_w  = (const float*)d_in[23];
    const float* fus_b  = (const float*)d_in[24];

    dim3 gl(128, 2);
    for (int br = 0; br < 2; ++br) {
        const float* pw = br ? sp_w : tp_w;
        const float* pb = br ? sp_b : tp_b;
        int base = 5 + br * 8;
        const float* qw = (const float*)d_in[base + 0];
        const float* qb = (const float*)d_in[base + 1];
        const float* kw = (const float*)d_in[base + 2];
        const float* kb = (const float*)d_in[base + 3];
        const float* vw = (const float*)d_in[base + 4];
        const float* vb = (const float*)d_in[base + 5];
        const float* ow = (const float*)d_in[base + 6];
        const float* ob = (const float*)d_in[base + 7];

        lin_kernel<256><<<gl, 256, 0, stream>>>(x, 0, pw, pb, OFF_PROJ);
        lin3_kernel<128><<<dim3(128, 2, 3), 256, 0, stream>>>(
            OFF_PROJ, qw, qb, OFF_Q, kw, kb, OFF_K, vw, vb, OFF_V);
        for (int chunk = 0; chunk < 2; ++chunk) {
            score_kernel<<<dim3(32, 32, CHD), 256, 0, stream>>>(OFF_Q, OFF_K, chunk);
            topk_kernel<<<CHD * 512, 256, 0, stream>>>(OFF_Q, OFF_K, OFF_V,
                                                       OFF_ATT, chunk);
        }
        lin_kernel<128><<<gl, 256, 0, stream>>>(nullptr, OFF_ATT, ow, ob,
                                                br ? OFF_SB : OFF_T);
    }
    concat_kernel<<<8192, 256, 0, stream>>>();
    lin3_kernel<256><<<dim3(128, 2, 2), 256, 0, stream>>>(
        OFF_CAT, gate_w, gate_b, OFF_Q, fus_w, fus_b, OFF_K,
        (const float*)nullptr, (const float*)nullptr, 0);
    fuse_kernel<<<4096, 256, 0, stream>>>((float*)d_out);
}